// Round 9
// baseline (666.038 us; speedup 1.0000x reference)
//
#include <hip/hip_runtime.h>
#include <hip/hip_bf16.h>
#include <math.h>

// Problem constants
#define B_SZ 8
#define N_SZ 4096
#define C_SZ 128
#define K_SZ 16
#define NPOINT 1024            // N / POOL_RATE

// FPS config: 512 threads (8 waves, 2 per SIMD), 8 CONTIGUOUS points/thread
#define FPS_T 512
#define FPS_PAIRS 4            // 4 float2-pairs = 8 points per thread

typedef float vf2 __attribute__((ext_vector_type(2)));

// ---------------------------------------------------------------------------
// Wave64 f32 max chain via DPP (full-rate).
// bound_ctrl=1 feeds 0.0 into invalid lanes — distances are >= 0 so 0 is a
// safe identity. After row_shr 1/2/4/8 + row_bcast 15/31, lane 63 = wave max.
// ---------------------------------------------------------------------------
template <int CTRL>
__device__ __forceinline__ float dpp_fmax(float x) {
    int t = __builtin_amdgcn_update_dpp(0, __float_as_int(x), CTRL, 0xF, 0xF, true);
    return fmaxf(x, __int_as_float(t));
}
__device__ __forceinline__ float wave_fmax63(float x) {
    x = dpp_fmax<0x111>(x);  // row_shr:1
    x = dpp_fmax<0x112>(x);  // row_shr:2
    x = dpp_fmax<0x114>(x);  // row_shr:4
    x = dpp_fmax<0x118>(x);  // row_shr:8
    x = dpp_fmax<0x142>(x);  // row_bcast:15
    x = dpp_fmax<0x143>(x);  // row_bcast:31
    return x;                 // valid in lane 63
}
__device__ __forceinline__ unsigned long long kmax2(unsigned long long a,
                                                   unsigned long long b) {
    return a > b ? a : b;
}

// ---------------------------------------------------------------------------
// Kernel 1: transpose feature_map (B, C, N) -> fmT (B*N, C)
// ---------------------------------------------------------------------------
__global__ void transpose_fm(const float* __restrict__ fm, float* __restrict__ fmT) {
    __shared__ float tile[32][33];
    const int b  = blockIdx.z;
    const int c0 = blockIdx.y * 32;
    const int n0 = blockIdx.x * 32;
    const int tx = threadIdx.x;   // 0..31
    const int ty = threadIdx.y;   // 0..7
    const float* p = fm + (size_t)b * C_SZ * N_SZ;
#pragma unroll
    for (int i = 0; i < 4; i++) {
        tile[ty + i * 8][tx] = p[(size_t)(c0 + ty + i * 8) * N_SZ + n0 + tx];
    }
    __syncthreads();
    float* q = fmT + (size_t)b * N_SZ * C_SZ;
#pragma unroll
    for (int i = 0; i < 4; i++) {
        q[(size_t)(n0 + ty + i * 8) * C_SZ + c0 + tx] = tile[tx][ty + i * 8];
    }
}

// ---------------------------------------------------------------------------
// Kernel 2: FPS, one block (512 threads, 8 waves — 2 per SIMD) per batch.
// Bit-exact numpy semantics: d=((x-cx)^2+(y-cy)^2)+(z-cz)^2 per-op rounding
// (contract/reassoc off), min then FIRST-index argmax.
//
// Layout: thread tid owns contiguous points [tid*8, tid*8+8). Within a wave,
// lane order == point-index order, so the wave argmax is:
//   f32 DPP max chain -> readlane(63) -> ballot(bv==wmax) -> ffs ->
//   readlane(bn, first)   (min n among ties, exact)
// Per-lane reverse scan gives min j (= min n) within the lane.
// Cross-wave: packed u64 key (dist<<32)|(4095-n), max => max dist, min n.
// One barrier per iteration; no global traffic in the loop.
// 2 waves/SIMD: each wave's DPP/LDS dependent-stall gaps are filled by its
// SIMD-sibling's issue — the R8 tail (~525 cyc at lockstep 1-wave/SIMD)
// becomes mostly hidden.
// ---------------------------------------------------------------------------
__global__ __launch_bounds__(FPS_T) void fps_kernel(
        const float* __restrict__ verts,   // (B, 3, N)
        float* __restrict__ out_vp,        // (B, 3, NPOINT)
        int* __restrict__ cents)           // (B, NPOINT)
{
#pragma clang fp contract(off)
#pragma clang fp reassociate(off)
    __shared__ float4 sp[N_SZ];                       // 64 KB xyz (w unused)
    __shared__ int    scent[NPOINT];                  //  4 KB
    __shared__ alignas(16) unsigned long long ckey[2][8];

    const int b    = blockIdx.x;
    const int tid  = threadIdx.x;
    const int lane = tid & 63;
    const int wid  = tid >> 6;
    const float* vb = verts + (size_t)b * 3 * N_SZ;

    // stage xyz into LDS (coalesced global loads, conflict-free LDS writes)
    for (int n = tid; n < N_SZ; n += FPS_T) {
        sp[n] = make_float4(vb[n], vb[N_SZ + n], vb[2 * N_SZ + n], 0.0f);
    }

    // contiguous per-thread register copy via coalesced float4 loads
    const float4* vx4 = (const float4*)vb;
    const float4* vy4 = (const float4*)(vb + N_SZ);
    const float4* vz4 = (const float4*)(vb + 2 * N_SZ);
    vf2 px[FPS_PAIRS], py[FPS_PAIRS], pz[FPS_PAIRS], dd[FPS_PAIRS];
#pragma unroll
    for (int k = 0; k < 2; k++) {
        const float4 x = vx4[tid * 2 + k];
        const float4 y = vy4[tid * 2 + k];
        const float4 z = vz4[tid * 2 + k];
        px[2 * k] = (vf2){x.x, x.y}; px[2 * k + 1] = (vf2){x.z, x.w};
        py[2 * k] = (vf2){y.x, y.y}; py[2 * k + 1] = (vf2){y.z, y.w};
        pz[2 * k] = (vf2){z.x, z.y}; pz[2 * k + 1] = (vf2){z.z, z.w};
        dd[2 * k]     = (vf2){1e10f, 1e10f};
        dd[2 * k + 1] = (vf2){1e10f, 1e10f};
    }
    __syncthreads();

    int ci = 0;
    const float4 c0 = sp[0];
    float cx = c0.x, cy = c0.y, cz = c0.z;

    for (int i = 0; i < NPOINT; i++) {
        if (tid == 0) scent[i] = ci;

        const vf2 cx2 = (vf2){cx, cx};
        const vf2 cy2 = (vf2){cy, cy};
        const vf2 cz2 = (vf2){cz, cz};

        float m = -1.0f;                   // running max (v_max3 per pair)
#pragma unroll
        for (int p = 0; p < FPS_PAIRS; p++) {
            const vf2 dx = px[p] - cx2;
            const vf2 dy = py[p] - cy2;
            const vf2 dz = pz[p] - cz2;
            vf2 s = dx * dx + dy * dy;     // contract off => mul,mul,add
            s = s + dz * dz;               // ((x^2+y^2)+z^2) order
            vf2 d;
            d.x = fminf(dd[p].x, s.x);
            d.y = fminf(dd[p].y, s.y);
            dd[p] = d;
            m = fmaxf(m, fmaxf(d.x, d.y)); // folds to v_max3_f32
        }
        const float bv = m;

        // reverse scan: lowest j with dd[j] == bv (max is a selection =>
        // exact bitwise compare); n = tid*8 + j so min j == min n in-lane
        int bj = 0;
#pragma unroll
        for (int j = 7; j >= 0; j--) {
            const float v = (j & 1) ? dd[j >> 1].y : dd[j >> 1].x;
            if (v == bv) bj = j;
        }
        const int bn = (tid << 3) | bj;    // global point index

        // wave argmax: f32 chain + ballot + first-lane readback
        const float wm = wave_fmax63(bv);
        const float wmax = __int_as_float(
            __builtin_amdgcn_readlane(__float_as_int(wm), 63));
        const unsigned long long mask = __ballot(bv == wmax);
        const int first = __ffsll(mask) - 1;
        const unsigned nw = (unsigned)__builtin_amdgcn_readlane(bn, first);

        const unsigned long long wkey =
            ((unsigned long long)__float_as_uint(wmax) << 32) |
            (unsigned long long)(4095u - nw);

        const int par = i & 1;
        if (lane == 0) ckey[par][wid] = wkey;
        __syncthreads();

        // all threads redundantly resolve the 8-way final (no 2nd barrier:
        // parity double-buffer makes the next write race-free)
        const ulonglong2* kb = (const ulonglong2*)(&ckey[par][0]);
        const ulonglong2 a0 = kb[0], a1 = kb[1], a2 = kb[2], a3 = kb[3];
        const unsigned long long q0 = kmax2(a0.x, a0.y);
        const unsigned long long q1 = kmax2(a1.x, a1.y);
        const unsigned long long q2 = kmax2(a2.x, a2.y);
        const unsigned long long q3 = kmax2(a3.x, a3.y);
        const unsigned long long kk = kmax2(kmax2(q0, q1), kmax2(q2, q3));

        ci = (int)(4095u - (unsigned)kk);
        const float4 c = sp[ci];
        cx = c.x; cy = c.y; cz = c.z;
    }
    __syncthreads();

    // epilogue: coalesced writes of cents + vertices_pool
    for (int i = tid; i < NPOINT; i += FPS_T) {
        const int cc = scent[i];
        const float4 v = sp[cc];
        cents[b * NPOINT + i] = cc;
        out_vp[(b * 3 + 0) * NPOINT + i] = v.x;
        out_vp[(b * 3 + 1) * NPOINT + i] = v.y;
        out_vp[(b * 3 + 2) * NPOINT + i] = v.z;
    }
}

// ---------------------------------------------------------------------------
// Kernel 3: gather+maxpool selected rows AND transpose to (B, C, NPOINT).
// 16 waves per block; wave w pools point j0+w (64 lanes x float2 = 128 ch),
// stages the 16x128 tile in LDS, then writes channel-major 64B segments.
// ---------------------------------------------------------------------------
#define GT_J 16
__global__ __launch_bounds__(1024) void pool_gather_t(
        const float* __restrict__ fmT,     // (B*N, C)
        const int* __restrict__ idx,       // (B*N*K), values in [0, B*N)
        const int* __restrict__ cents,     // (B*NPOINT)
        float* __restrict__ out_fp)        // (B, C, NPOINT)
{
    __shared__ float tile[C_SZ][GT_J + 1];
    const int tid  = threadIdx.x;
    const int lane = tid & 63;
    const int w    = tid >> 6;
    const int j0   = blockIdx.x * GT_J;    // global pooled-point base
    const int gp   = j0 + w;
    const int b    = gp >> 10;             // NPOINT = 1024
    const int ci   = cents[gp];
    const int* ip  = idx + ((size_t)(b * N_SZ + ci)) * K_SZ;
    const float2* src = (const float2*)fmT;

    float2 acc = make_float2(-INFINITY, -INFINITY);
#pragma unroll
    for (int k = 0; k < K_SZ; k++) {
        const int p = ip[k];
        const float2 v = src[(size_t)p * (C_SZ / 2) + lane];
        acc.x = fmaxf(acc.x, v.x);
        acc.y = fmaxf(acc.y, v.y);
    }
    tile[2 * lane][w]     = acc.x;
    tile[2 * lane + 1][w] = acc.y;
    __syncthreads();

    float* q = out_fp + (size_t)b * C_SZ * NPOINT + (j0 & (NPOINT - 1));
#pragma unroll
    for (int it = 0; it < 2; it++) {
        const int e  = tid + it * 1024;
        const int c  = e >> 4;
        const int jj = e & (GT_J - 1);
        q[(size_t)c * NPOINT + jj] = tile[c][jj];
    }
}

// ---------------------------------------------------------------------------
extern "C" void kernel_launch(void* const* d_in, const int* in_sizes, int n_in,
                              void* d_out, int out_size, void* d_ws, size_t ws_size,
                              hipStream_t stream) {
    const float* verts = (const float*)d_in[0];   // (B,3,N) f32
    const float* fm    = (const float*)d_in[1];   // (B,C,N) f32
    const int*   idx   = (const int*)d_in[2];     // (B*N*K) i32

    float* out    = (float*)d_out;
    float* out_vp = out;                               // B*3*NPOINT = 24576
    float* out_fp = out + (size_t)B_SZ * 3 * NPOINT;   // B*C*NPOINT

    char* ws = (char*)d_ws;
    float* fmT   = (float*)ws;                                     // 16 MB
    int*   cents = (int*)(ws + (size_t)B_SZ * N_SZ * C_SZ * 4);    // 32 KB

    dim3 tb(32, 8);
    transpose_fm<<<dim3(N_SZ / 32, C_SZ / 32, B_SZ), tb, 0, stream>>>(fm, fmT);
    fps_kernel<<<B_SZ, FPS_T, 0, stream>>>(verts, out_vp, cents);
    pool_gather_t<<<(B_SZ * NPOINT) / GT_J, 1024, 0, stream>>>(fmT, idx, cents, out_fp);
}

// Round 10
// 624.427 us; speedup vs baseline: 1.0666x; 1.0666x over previous
//
#include <hip/hip_runtime.h>
#include <hip/hip_bf16.h>
#include <math.h>

// Problem constants
#define B_SZ 8
#define N_SZ 4096
#define C_SZ 128
#define K_SZ 16
#define NPOINT 1024            // N / POOL_RATE

// FPS config: 256 threads (4 waves, 1 per SIMD), 16 CONTIGUOUS points/thread
// (R8 optimum — 512thr/2-waves-per-SIMD tested twice, loses on busy growth)
#define FPS_T 256
#define FPS_PAIRS 8            // 8 float2-pairs = 16 points per thread

#define TR_BLOCKS 512          // transpose companion blocks
#define TR_TILES  8            // 32x32 tiles per companion block (512*8=4096)

typedef float vf2 __attribute__((ext_vector_type(2)));

// ---------------------------------------------------------------------------
// Wave64 f32 max chain via DPP (full-rate).
// bound_ctrl=1 feeds 0.0 into invalid lanes — distances are >= 0 so 0 is a
// safe identity. After row_shr 1/2/4/8 + row_bcast 15/31, lane 63 = wave max.
// ---------------------------------------------------------------------------
template <int CTRL>
__device__ __forceinline__ float dpp_fmax(float x) {
    int t = __builtin_amdgcn_update_dpp(0, __float_as_int(x), CTRL, 0xF, 0xF, true);
    return fmaxf(x, __int_as_float(t));
}
__device__ __forceinline__ float wave_fmax63(float x) {
    x = dpp_fmax<0x111>(x);  // row_shr:1
    x = dpp_fmax<0x112>(x);  // row_shr:2
    x = dpp_fmax<0x114>(x);  // row_shr:4
    x = dpp_fmax<0x118>(x);  // row_shr:8
    x = dpp_fmax<0x142>(x);  // row_bcast:15
    x = dpp_fmax<0x143>(x);  // row_bcast:31
    return x;                 // valid in lane 63
}
__device__ __forceinline__ unsigned long long kmax2(unsigned long long a,
                                                   unsigned long long b) {
    return a > b ? a : b;
}

// ---------------------------------------------------------------------------
// Kernel A: blocks 0..7 = FPS (one per batch); blocks 8.. = feature-map
// transpose (B,C,N)->(B*N,C), TR_TILES 32x32 tiles each.
//
// LDS-EXCLUSION: static LDS is padded to ~86.5 KB so only ONE block fits per
// CU (2x86.5 > 160). This guarantees transpose blocks can never co-reside
// with (and steal issue from) an fps block — R4's fusion failure mode.
// ---------------------------------------------------------------------------
__global__ __launch_bounds__(FPS_T) void fps_fused(
        const float* __restrict__ verts,   // (B, 3, N)
        const float* __restrict__ fm,      // (B, C, N)
        float* __restrict__ fmT,           // (B*N, C)
        float* __restrict__ out_vp,        // (B, 3, NPOINT)
        int* __restrict__ cents)           // (B, NPOINT)
{
#pragma clang fp contract(off)
#pragma clang fp reassociate(off)
    __shared__ float4 sp[N_SZ];                       // 64 KB xyz (w unused)
    __shared__ int    scent[NPOINT];                  //  4 KB
    __shared__ alignas(16) unsigned long long ckey[2][4];
    __shared__ float  trtile[2][32 * 33];             // 8.25KB (transpose path)
    __shared__ float  lds_pad[2048];                  // 8 KB -> total ~86.5 KB

    const int tid = threadIdx.x;

    if (blockIdx.x >= B_SZ) {
        // ---------------- transpose path: TR_TILES 32x32 tiles ------------
        const int tx = tid & 31;
        const int ty = tid >> 5;           // 0..7
        // touch lds_pad so it is not stripped (never true at runtime)
        if (tid == 0xFFFF) lds_pad[0] = 1.0f;
        for (int tt = 0; tt < TR_TILES; tt++) {
            const int g  = (blockIdx.x - B_SZ) * TR_TILES + tt;
            const int b  = g >> 9;                       // 512 tiles/batch
            const int r  = g & 511;
            const int n0 = (r & 127) * 32;
            const int c0 = (r >> 7) * 32;
            float* tl = trtile[tt & 1];
            const float* p = fm + (size_t)b * C_SZ * N_SZ;
#pragma unroll
            for (int i = 0; i < 4; i++) {
                tl[(ty + i * 8) * 33 + tx] =
                    p[(size_t)(c0 + ty + i * 8) * N_SZ + n0 + tx];
            }
            __syncthreads();
            float* q = fmT + (size_t)b * N_SZ * C_SZ;
#pragma unroll
            for (int i = 0; i < 4; i++) {
                q[(size_t)(n0 + ty + i * 8) * C_SZ + c0 + tx] =
                    tl[tx * 33 + ty + i * 8];
            }
            __syncthreads();
        }
        return;
    }

    // -------------------------------- FPS path (R8, unchanged) ------------
    // Bit-exact numpy semantics: d=((x-cx)^2+(y-cy)^2)+(z-cz)^2 per-op
    // rounding (contract/reassoc off), min then FIRST-index argmax.
    // Thread tid owns contiguous points [tid*16, tid*16+16); wave argmax =
    // f32 DPP chain -> readlane(63) -> ballot -> ffs -> readlane(bn, first);
    // cross-wave via packed u64 key (dist<<32)|(4095-n); one barrier/iter.
    const int b    = blockIdx.x;
    const int lane = tid & 63;
    const int wid  = tid >> 6;
    const float* vb = verts + (size_t)b * 3 * N_SZ;

    // stage xyz into LDS (coalesced global loads, conflict-free LDS writes)
    for (int n = tid; n < N_SZ; n += FPS_T) {
        sp[n] = make_float4(vb[n], vb[N_SZ + n], vb[2 * N_SZ + n], 0.0f);
    }

    // contiguous per-thread register copy via coalesced float4 loads
    const float4* vx4 = (const float4*)vb;
    const float4* vy4 = (const float4*)(vb + N_SZ);
    const float4* vz4 = (const float4*)(vb + 2 * N_SZ);
    vf2 px[FPS_PAIRS], py[FPS_PAIRS], pz[FPS_PAIRS], dd[FPS_PAIRS];
#pragma unroll
    for (int k = 0; k < 4; k++) {
        const float4 x = vx4[tid * 4 + k];
        const float4 y = vy4[tid * 4 + k];
        const float4 z = vz4[tid * 4 + k];
        px[2 * k] = (vf2){x.x, x.y}; px[2 * k + 1] = (vf2){x.z, x.w};
        py[2 * k] = (vf2){y.x, y.y}; py[2 * k + 1] = (vf2){y.z, y.w};
        pz[2 * k] = (vf2){z.x, z.y}; pz[2 * k + 1] = (vf2){z.z, z.w};
        dd[2 * k]     = (vf2){1e10f, 1e10f};
        dd[2 * k + 1] = (vf2){1e10f, 1e10f};
    }
    __syncthreads();

    int ci = 0;
    const float4 c0 = sp[0];
    float cx = c0.x, cy = c0.y, cz = c0.z;

    for (int i = 0; i < NPOINT; i++) {
        if (tid == 0) scent[i] = ci;

        const vf2 cx2 = (vf2){cx, cx};
        const vf2 cy2 = (vf2){cy, cy};
        const vf2 cz2 = (vf2){cz, cz};

        float m = -1.0f;                   // running max (v_max3 per pair)
#pragma unroll
        for (int p = 0; p < FPS_PAIRS; p++) {
            const vf2 dx = px[p] - cx2;
            const vf2 dy = py[p] - cy2;
            const vf2 dz = pz[p] - cz2;
            vf2 s = dx * dx + dy * dy;     // contract off => mul,mul,add
            s = s + dz * dz;               // ((x^2+y^2)+z^2) order
            vf2 d;
            d.x = fminf(dd[p].x, s.x);
            d.y = fminf(dd[p].y, s.y);
            dd[p] = d;
            m = fmaxf(m, fmaxf(d.x, d.y)); // folds to v_max3_f32
        }
        const float bv = m;

        // reverse scan: lowest j with dd[j] == bv (max is a selection =>
        // exact bitwise compare); n = tid*16 + j so min j == min n in-lane
        int bj = 0;
#pragma unroll
        for (int j = 15; j >= 0; j--) {
            const float v = (j & 1) ? dd[j >> 1].y : dd[j >> 1].x;
            if (v == bv) bj = j;
        }
        const int bn = (tid << 4) | bj;    // global point index

        // wave argmax: f32 chain + ballot + first-lane readback
        const float wm = wave_fmax63(bv);
        const float wmax = __int_as_float(
            __builtin_amdgcn_readlane(__float_as_int(wm), 63));
        const unsigned long long mask = __ballot(bv == wmax);
        const int first = __ffsll(mask) - 1;
        const unsigned nw = (unsigned)__builtin_amdgcn_readlane(bn, first);

        const unsigned long long wkey =
            ((unsigned long long)__float_as_uint(wmax) << 32) |
            (unsigned long long)(4095u - nw);

        const int par = i & 1;
        if (lane == 0) ckey[par][wid] = wkey;
        __syncthreads();

        // all threads redundantly resolve the 4-way final (no 2nd barrier:
        // parity double-buffer makes the next write race-free)
        const ulonglong2* kb = (const ulonglong2*)(&ckey[par][0]);
        const ulonglong2 k01 = kb[0], k23 = kb[1];
        const unsigned long long kk =
            kmax2(kmax2(k01.x, k01.y), kmax2(k23.x, k23.y));

        ci = (int)(4095u - (unsigned)kk);
        const float4 c = sp[ci];
        cx = c.x; cy = c.y; cz = c.z;
    }
    __syncthreads();

    // epilogue: coalesced writes of cents + vertices_pool
    for (int i = tid; i < NPOINT; i += FPS_T) {
        const int cc = scent[i];
        const float4 v = sp[cc];
        cents[b * NPOINT + i] = cc;
        out_vp[(b * 3 + 0) * NPOINT + i] = v.x;
        out_vp[(b * 3 + 1) * NPOINT + i] = v.y;
        out_vp[(b * 3 + 2) * NPOINT + i] = v.z;
    }
}

// ---------------------------------------------------------------------------
// Kernel B: gather+maxpool selected rows AND transpose to (B, C, NPOINT).
// 16 waves per block; wave w pools point j0+w (64 lanes x float2 = 128 ch),
// stages the 16x128 tile in LDS, then writes channel-major 64B segments.
// ---------------------------------------------------------------------------
#define GT_J 16
__global__ __launch_bounds__(1024) void pool_gather_t(
        const float* __restrict__ fmT,     // (B*N, C)
        const int* __restrict__ idx,       // (B*N*K), values in [0, B*N)
        const int* __restrict__ cents,     // (B*NPOINT)
        float* __restrict__ out_fp)        // (B, C, NPOINT)
{
    __shared__ float tile[C_SZ][GT_J + 1];
    const int tid  = threadIdx.x;
    const int lane = tid & 63;
    const int w    = tid >> 6;
    const int j0   = blockIdx.x * GT_J;    // global pooled-point base
    const int gp   = j0 + w;
    const int b    = gp >> 10;             // NPOINT = 1024
    const int ci   = cents[gp];
    const int* ip  = idx + ((size_t)(b * N_SZ + ci)) * K_SZ;
    const float2* src = (const float2*)fmT;

    float2 acc = make_float2(-INFINITY, -INFINITY);
#pragma unroll
    for (int k = 0; k < K_SZ; k++) {
        const int p = ip[k];
        const float2 v = src[(size_t)p * (C_SZ / 2) + lane];
        acc.x = fmaxf(acc.x, v.x);
        acc.y = fmaxf(acc.y, v.y);
    }
    tile[2 * lane][w]     = acc.x;
    tile[2 * lane + 1][w] = acc.y;
    __syncthreads();

    float* q = out_fp + (size_t)b * C_SZ * NPOINT + (j0 & (NPOINT - 1));
#pragma unroll
    for (int it = 0; it < 2; it++) {
        const int e  = tid + it * 1024;
        const int c  = e >> 4;
        const int jj = e & (GT_J - 1);
        q[(size_t)c * NPOINT + jj] = tile[c][jj];
    }
}

// ---------------------------------------------------------------------------
extern "C" void kernel_launch(void* const* d_in, const int* in_sizes, int n_in,
                              void* d_out, int out_size, void* d_ws, size_t ws_size,
                              hipStream_t stream) {
    const float* verts = (const float*)d_in[0];   // (B,3,N) f32
    const float* fm    = (const float*)d_in[1];   // (B,C,N) f32
    const int*   idx   = (const int*)d_in[2];     // (B*N*K) i32

    float* out    = (float*)d_out;
    float* out_vp = out;                               // B*3*NPOINT = 24576
    float* out_fp = out + (size_t)B_SZ * 3 * NPOINT;   // B*C*NPOINT

    char* ws = (char*)d_ws;
    float* fmT   = (float*)ws;                                     // 16 MB
    int*   cents = (int*)(ws + (size_t)B_SZ * N_SZ * C_SZ * 4);    // 32 KB

    fps_fused<<<B_SZ + TR_BLOCKS, FPS_T, 0, stream>>>(verts, fm, fmT, out_vp, cents);
    pool_gather_t<<<(B_SZ * NPOINT) / GT_J, 1024, 0, stream>>>(fmT, idx, cents, out_fp);
}

// Round 11
// 622.828 us; speedup vs baseline: 1.0694x; 1.0026x over previous
//
#include <hip/hip_runtime.h>
#include <hip/hip_bf16.h>
#include <math.h>

// Problem constants
#define B_SZ 8
#define N_SZ 4096
#define C_SZ 128
#define K_SZ 16
#define NPOINT 1024            // N / POOL_RATE

// FPS config: 256 threads (4 waves, 1 per SIMD), 16 CONTIGUOUS points/thread
// (R8 optimum — 512thr/2-waves-per-SIMD tested twice, loses on busy growth)
#define FPS_T 256
#define FPS_PAIRS 8            // 8 float2-pairs = 16 points per thread

#define TR_BLOCKS 512          // transpose companion blocks
#define TR_TILES  8            // 32x32 tiles per companion block (512*8=4096)

// Dynamic LDS pad: static LDS is 78336 B (R10 measured); +12288 dynamic
// = 90624 B per block => 2 blocks can never share a 160 KB CU. Unlike a
// static pad array (stripped by the compiler in R10 — provably-false guard),
// launch-configured dynamic LDS is reserved unconditionally.
#define DYN_PAD 12288

typedef float vf2 __attribute__((ext_vector_type(2)));

// ---------------------------------------------------------------------------
// Wave64 f32 max chain via DPP (full-rate).
// bound_ctrl=1 feeds 0.0 into invalid lanes — distances are >= 0 so 0 is a
// safe identity. After row_shr 1/2/4/8 + row_bcast 15/31, lane 63 = wave max.
// ---------------------------------------------------------------------------
template <int CTRL>
__device__ __forceinline__ float dpp_fmax(float x) {
    int t = __builtin_amdgcn_update_dpp(0, __float_as_int(x), CTRL, 0xF, 0xF, true);
    return fmaxf(x, __int_as_float(t));
}
__device__ __forceinline__ float wave_fmax63(float x) {
    x = dpp_fmax<0x111>(x);  // row_shr:1
    x = dpp_fmax<0x112>(x);  // row_shr:2
    x = dpp_fmax<0x114>(x);  // row_shr:4
    x = dpp_fmax<0x118>(x);  // row_shr:8
    x = dpp_fmax<0x142>(x);  // row_bcast:15
    x = dpp_fmax<0x143>(x);  // row_bcast:31
    return x;                 // valid in lane 63
}
__device__ __forceinline__ unsigned long long kmax2(unsigned long long a,
                                                   unsigned long long b) {
    return a > b ? a : b;
}

// ---------------------------------------------------------------------------
// Kernel A: blocks 0..7 = FPS (one per batch); blocks 8.. = feature-map
// transpose (B,C,N)->(B*N,C), TR_TILES 32x32 tiles each. Dynamic-LDS pad
// guarantees 1 block/CU, so companions never steal fps issue slots.
// ---------------------------------------------------------------------------
__global__ __launch_bounds__(FPS_T) void fps_fused(
        const float* __restrict__ verts,   // (B, 3, N)
        const float* __restrict__ fm,      // (B, C, N)
        float* __restrict__ fmT,           // (B*N, C)
        float* __restrict__ out_vp,        // (B, 3, NPOINT)
        int* __restrict__ cents)           // (B, NPOINT)
{
#pragma clang fp contract(off)
#pragma clang fp reassociate(off)
    __shared__ float4 sp[N_SZ];                       // 64 KB xyz (w unused)
    __shared__ int    scent[NPOINT];                  //  4 KB
    __shared__ alignas(16) unsigned long long ckey[2][4];
    __shared__ float  trtile[2][32 * 33];             // 8.25KB (transpose path)

    const int tid = threadIdx.x;

    if (blockIdx.x >= B_SZ) {
        // ---------------- transpose path: TR_TILES 32x32 tiles ------------
        const int tx = tid & 31;
        const int ty = tid >> 5;           // 0..7
        for (int tt = 0; tt < TR_TILES; tt++) {
            const int g  = (blockIdx.x - B_SZ) * TR_TILES + tt;
            const int b  = g >> 9;                       // 512 tiles/batch
            const int r  = g & 511;
            const int n0 = (r & 127) * 32;
            const int c0 = (r >> 7) * 32;
            float* tl = trtile[tt & 1];
            const float* p = fm + (size_t)b * C_SZ * N_SZ;
#pragma unroll
            for (int i = 0; i < 4; i++) {
                tl[(ty + i * 8) * 33 + tx] =
                    p[(size_t)(c0 + ty + i * 8) * N_SZ + n0 + tx];
            }
            __syncthreads();
            float* q = fmT + (size_t)b * N_SZ * C_SZ;
#pragma unroll
            for (int i = 0; i < 4; i++) {
                q[(size_t)(n0 + ty + i * 8) * C_SZ + c0 + tx] =
                    tl[tx * 33 + ty + i * 8];
            }
            __syncthreads();
        }
        return;
    }

    // -------------------------------- FPS path (R8, unchanged) ------------
    // Bit-exact numpy semantics: d=((x-cx)^2+(y-cy)^2)+(z-cz)^2 per-op
    // rounding (contract/reassoc off), min then FIRST-index argmax.
    // Thread tid owns contiguous points [tid*16, tid*16+16); wave argmax =
    // f32 DPP chain -> readlane(63) -> ballot -> ffs -> readlane(bn, first);
    // cross-wave via packed u64 key (dist<<32)|(4095-n); one barrier/iter.
    const int b    = blockIdx.x;
    const int lane = tid & 63;
    const int wid  = tid >> 6;
    const float* vb = verts + (size_t)b * 3 * N_SZ;

    // stage xyz into LDS (coalesced global loads, conflict-free LDS writes)
    for (int n = tid; n < N_SZ; n += FPS_T) {
        sp[n] = make_float4(vb[n], vb[N_SZ + n], vb[2 * N_SZ + n], 0.0f);
    }

    // contiguous per-thread register copy via coalesced float4 loads
    const float4* vx4 = (const float4*)vb;
    const float4* vy4 = (const float4*)(vb + N_SZ);
    const float4* vz4 = (const float4*)(vb + 2 * N_SZ);
    vf2 px[FPS_PAIRS], py[FPS_PAIRS], pz[FPS_PAIRS], dd[FPS_PAIRS];
#pragma unroll
    for (int k = 0; k < 4; k++) {
        const float4 x = vx4[tid * 4 + k];
        const float4 y = vy4[tid * 4 + k];
        const float4 z = vz4[tid * 4 + k];
        px[2 * k] = (vf2){x.x, x.y}; px[2 * k + 1] = (vf2){x.z, x.w};
        py[2 * k] = (vf2){y.x, y.y}; py[2 * k + 1] = (vf2){y.z, y.w};
        pz[2 * k] = (vf2){z.x, z.y}; pz[2 * k + 1] = (vf2){z.z, z.w};
        dd[2 * k]     = (vf2){1e10f, 1e10f};
        dd[2 * k + 1] = (vf2){1e10f, 1e10f};
    }
    __syncthreads();

    int ci = 0;
    const float4 c0 = sp[0];
    float cx = c0.x, cy = c0.y, cz = c0.z;

    for (int i = 0; i < NPOINT; i++) {
        if (tid == 0) scent[i] = ci;

        const vf2 cx2 = (vf2){cx, cx};
        const vf2 cy2 = (vf2){cy, cy};
        const vf2 cz2 = (vf2){cz, cz};

        float m = -1.0f;                   // running max (v_max3 per pair)
#pragma unroll
        for (int p = 0; p < FPS_PAIRS; p++) {
            const vf2 dx = px[p] - cx2;
            const vf2 dy = py[p] - cy2;
            const vf2 dz = pz[p] - cz2;
            vf2 s = dx * dx + dy * dy;     // contract off => mul,mul,add
            s = s + dz * dz;               // ((x^2+y^2)+z^2) order
            vf2 d;
            d.x = fminf(dd[p].x, s.x);
            d.y = fminf(dd[p].y, s.y);
            dd[p] = d;
            m = fmaxf(m, fmaxf(d.x, d.y)); // folds to v_max3_f32
        }
        const float bv = m;

        // reverse scan: lowest j with dd[j] == bv (max is a selection =>
        // exact bitwise compare); n = tid*16 + j so min j == min n in-lane
        int bj = 0;
#pragma unroll
        for (int j = 15; j >= 0; j--) {
            const float v = (j & 1) ? dd[j >> 1].y : dd[j >> 1].x;
            if (v == bv) bj = j;
        }
        const int bn = (tid << 4) | bj;    // global point index

        // wave argmax: f32 chain + ballot + first-lane readback
        const float wm = wave_fmax63(bv);
        const float wmax = __int_as_float(
            __builtin_amdgcn_readlane(__float_as_int(wm), 63));
        const unsigned long long mask = __ballot(bv == wmax);
        const int first = __ffsll(mask) - 1;
        const unsigned nw = (unsigned)__builtin_amdgcn_readlane(bn, first);

        const unsigned long long wkey =
            ((unsigned long long)__float_as_uint(wmax) << 32) |
            (unsigned long long)(4095u - nw);

        const int par = i & 1;
        if (lane == 0) ckey[par][wid] = wkey;
        __syncthreads();

        // all threads redundantly resolve the 4-way final (no 2nd barrier:
        // parity double-buffer makes the next write race-free)
        const ulonglong2* kb = (const ulonglong2*)(&ckey[par][0]);
        const ulonglong2 k01 = kb[0], k23 = kb[1];
        const unsigned long long kk =
            kmax2(kmax2(k01.x, k01.y), kmax2(k23.x, k23.y));

        ci = (int)(4095u - (unsigned)kk);
        const float4 c = sp[ci];
        cx = c.x; cy = c.y; cz = c.z;
    }
    __syncthreads();

    // epilogue: coalesced writes of cents + vertices_pool
    for (int i = tid; i < NPOINT; i += FPS_T) {
        const int cc = scent[i];
        const float4 v = sp[cc];
        cents[b * NPOINT + i] = cc;
        out_vp[(b * 3 + 0) * NPOINT + i] = v.x;
        out_vp[(b * 3 + 1) * NPOINT + i] = v.y;
        out_vp[(b * 3 + 2) * NPOINT + i] = v.z;
    }
}

// ---------------------------------------------------------------------------
// Kernel B: gather+maxpool selected rows AND transpose to (B, C, NPOINT).
// 16 waves per block; wave w pools point j0+w (64 lanes x float2 = 128 ch),
// stages the 16x128 tile in LDS, then writes channel-major 64B segments.
// ---------------------------------------------------------------------------
#define GT_J 16
__global__ __launch_bounds__(1024) void pool_gather_t(
        const float* __restrict__ fmT,     // (B*N, C)
        const int* __restrict__ idx,       // (B*N*K), values in [0, B*N)
        const int* __restrict__ cents,     // (B*NPOINT)
        float* __restrict__ out_fp)        // (B, C, NPOINT)
{
    __shared__ float tile[C_SZ][GT_J + 1];
    const int tid  = threadIdx.x;
    const int lane = tid & 63;
    const int w    = tid >> 6;
    const int j0   = blockIdx.x * GT_J;    // global pooled-point base
    const int gp   = j0 + w;
    const int b    = gp >> 10;             // NPOINT = 1024
    const int ci   = cents[gp];
    const int* ip  = idx + ((size_t)(b * N_SZ + ci)) * K_SZ;
    const float2* src = (const float2*)fmT;

    float2 acc = make_float2(-INFINITY, -INFINITY);
#pragma unroll
    for (int k = 0; k < K_SZ; k++) {
        const int p = ip[k];
        const float2 v = src[(size_t)p * (C_SZ / 2) + lane];
        acc.x = fmaxf(acc.x, v.x);
        acc.y = fmaxf(acc.y, v.y);
    }
    tile[2 * lane][w]     = acc.x;
    tile[2 * lane + 1][w] = acc.y;
    __syncthreads();

    float* q = out_fp + (size_t)b * C_SZ * NPOINT + (j0 & (NPOINT - 1));
#pragma unroll
    for (int it = 0; it < 2; it++) {
        const int e  = tid + it * 1024;
        const int c  = e >> 4;
        const int jj = e & (GT_J - 1);
        q[(size_t)c * NPOINT + jj] = tile[c][jj];
    }
}

// ---------------------------------------------------------------------------
extern "C" void kernel_launch(void* const* d_in, const int* in_sizes, int n_in,
                              void* d_out, int out_size, void* d_ws, size_t ws_size,
                              hipStream_t stream) {
    const float* verts = (const float*)d_in[0];   // (B,3,N) f32
    const float* fm    = (const float*)d_in[1];   // (B,C,N) f32
    const int*   idx   = (const int*)d_in[2];     // (B*N*K) i32

    float* out    = (float*)d_out;
    float* out_vp = out;                               // B*3*NPOINT = 24576
    float* out_fp = out + (size_t)B_SZ * 3 * NPOINT;   // B*C*NPOINT

    char* ws = (char*)d_ws;
    float* fmT   = (float*)ws;                                     // 16 MB
    int*   cents = (int*)(ws + (size_t)B_SZ * N_SZ * C_SZ * 4);    // 32 KB

    fps_fused<<<B_SZ + TR_BLOCKS, FPS_T, DYN_PAD, stream>>>(verts, fm, fmT, out_vp, cents);
    pool_gather_t<<<(B_SZ * NPOINT) / GT_J, 1024, 0, stream>>>(fmT, idx, cents, out_fp);
}

// Round 12
// 622.776 us; speedup vs baseline: 1.0695x; 1.0001x over previous
//
#include <hip/hip_runtime.h>
#include <hip/hip_bf16.h>
#include <math.h>

// Problem constants
#define B_SZ 8
#define N_SZ 4096
#define C_SZ 128
#define K_SZ 16
#define NPOINT 1024            // N / POOL_RATE

// FPS config: 256 threads (4 waves, 1 per SIMD), 16 CONTIGUOUS points/thread
// (R8 optimum — 512thr/2-waves-per-SIMD tested twice, loses on busy growth)
#define FPS_T 256
#define FPS_PAIRS 8            // 8 float2-pairs = 16 points per thread

#define TR_BLOCKS 512          // transpose companion blocks
#define TR_TILES  8            // 32x32 tiles per companion block (512*8=4096)

// Dynamic LDS: used as the transpose tile buffer (2*32*33*4 = 8448 B needed,
// 16384 B requested). static ~70144 + 16384 = ~86.5 KB per block =>
// 2 blocks can never share a 160 KB CU -> fps blocks own their CU.
// R10 lesson: a static pad behind a false guard gets stripped; R11 lesson:
// dynamicSharedMemBytes without extern __shared__ is dropped. This version
// declares AND uses extern __shared__ — unstrippable.
#define DYN_BYTES 16384

typedef float vf2 __attribute__((ext_vector_type(2)));

// ---------------------------------------------------------------------------
// Wave64 f32 max chain via DPP (full-rate).
// bound_ctrl=1 feeds 0.0 into invalid lanes — distances are >= 0 so 0 is a
// safe identity. After row_shr 1/2/4/8 + row_bcast 15/31, lane 63 = wave max.
// ---------------------------------------------------------------------------
template <int CTRL>
__device__ __forceinline__ float dpp_fmax(float x) {
    int t = __builtin_amdgcn_update_dpp(0, __float_as_int(x), CTRL, 0xF, 0xF, true);
    return fmaxf(x, __int_as_float(t));
}
__device__ __forceinline__ float wave_fmax63(float x) {
    x = dpp_fmax<0x111>(x);  // row_shr:1
    x = dpp_fmax<0x112>(x);  // row_shr:2
    x = dpp_fmax<0x114>(x);  // row_shr:4
    x = dpp_fmax<0x118>(x);  // row_shr:8
    x = dpp_fmax<0x142>(x);  // row_bcast:15
    x = dpp_fmax<0x143>(x);  // row_bcast:31
    return x;                 // valid in lane 63
}
__device__ __forceinline__ unsigned long long kmax2(unsigned long long a,
                                                   unsigned long long b) {
    return a > b ? a : b;
}

// ---------------------------------------------------------------------------
// Kernel A: blocks 0..7 = FPS (one per batch); blocks 8.. = feature-map
// transpose (B,C,N)->(B*N,C), TR_TILES 32x32 tiles each, tiles staged in
// DYNAMIC shared memory (see DYN_BYTES note).
// ---------------------------------------------------------------------------
__global__ __launch_bounds__(FPS_T) void fps_fused(
        const float* __restrict__ verts,   // (B, 3, N)
        const float* __restrict__ fm,      // (B, C, N)
        float* __restrict__ fmT,           // (B*N, C)
        float* __restrict__ out_vp,        // (B, 3, NPOINT)
        int* __restrict__ cents)           // (B, NPOINT)
{
#pragma clang fp contract(off)
#pragma clang fp reassociate(off)
    __shared__ float4 sp[N_SZ];                       // 64 KB xyz (w unused)
    __shared__ int    scent[NPOINT];                  //  4 KB
    __shared__ alignas(16) unsigned long long ckey[2][4];
    extern __shared__ float dynlds[];                 // transpose tiles

    const int tid = threadIdx.x;

    if (blockIdx.x >= B_SZ) {
        // ---------------- transpose path: TR_TILES 32x32 tiles ------------
        const int tx = tid & 31;
        const int ty = tid >> 5;           // 0..7
        for (int tt = 0; tt < TR_TILES; tt++) {
            const int g  = (blockIdx.x - B_SZ) * TR_TILES + tt;
            const int b  = g >> 9;                       // 512 tiles/batch
            const int r  = g & 511;
            const int n0 = (r & 127) * 32;
            const int c0 = (r >> 7) * 32;
            float* tl = dynlds + (tt & 1) * (32 * 33);
            const float* p = fm + (size_t)b * C_SZ * N_SZ;
#pragma unroll
            for (int i = 0; i < 4; i++) {
                tl[(ty + i * 8) * 33 + tx] =
                    p[(size_t)(c0 + ty + i * 8) * N_SZ + n0 + tx];
            }
            __syncthreads();
            float* q = fmT + (size_t)b * N_SZ * C_SZ;
#pragma unroll
            for (int i = 0; i < 4; i++) {
                q[(size_t)(n0 + ty + i * 8) * C_SZ + c0 + tx] =
                    tl[tx * 33 + ty + i * 8];
            }
            __syncthreads();
        }
        return;
    }

    // -------------------------------- FPS path (R8, unchanged) ------------
    // Bit-exact numpy semantics: d=((x-cx)^2+(y-cy)^2)+(z-cz)^2 per-op
    // rounding (contract/reassoc off), min then FIRST-index argmax.
    // Thread tid owns contiguous points [tid*16, tid*16+16); wave argmax =
    // f32 DPP chain -> readlane(63) -> ballot -> ffs -> readlane(bn, first);
    // cross-wave via packed u64 key (dist<<32)|(4095-n); one barrier/iter.
    const int b    = blockIdx.x;
    const int lane = tid & 63;
    const int wid  = tid >> 6;
    const float* vb = verts + (size_t)b * 3 * N_SZ;

    // stage xyz into LDS (coalesced global loads, conflict-free LDS writes)
    for (int n = tid; n < N_SZ; n += FPS_T) {
        sp[n] = make_float4(vb[n], vb[N_SZ + n], vb[2 * N_SZ + n], 0.0f);
    }

    // contiguous per-thread register copy via coalesced float4 loads
    const float4* vx4 = (const float4*)vb;
    const float4* vy4 = (const float4*)(vb + N_SZ);
    const float4* vz4 = (const float4*)(vb + 2 * N_SZ);
    vf2 px[FPS_PAIRS], py[FPS_PAIRS], pz[FPS_PAIRS], dd[FPS_PAIRS];
#pragma unroll
    for (int k = 0; k < 4; k++) {
        const float4 x = vx4[tid * 4 + k];
        const float4 y = vy4[tid * 4 + k];
        const float4 z = vz4[tid * 4 + k];
        px[2 * k] = (vf2){x.x, x.y}; px[2 * k + 1] = (vf2){x.z, x.w};
        py[2 * k] = (vf2){y.x, y.y}; py[2 * k + 1] = (vf2){y.z, y.w};
        pz[2 * k] = (vf2){z.x, z.y}; pz[2 * k + 1] = (vf2){z.z, z.w};
        dd[2 * k]     = (vf2){1e10f, 1e10f};
        dd[2 * k + 1] = (vf2){1e10f, 1e10f};
    }
    __syncthreads();

    int ci = 0;
    const float4 c0 = sp[0];
    float cx = c0.x, cy = c0.y, cz = c0.z;

    for (int i = 0; i < NPOINT; i++) {
        if (tid == 0) scent[i] = ci;

        const vf2 cx2 = (vf2){cx, cx};
        const vf2 cy2 = (vf2){cy, cy};
        const vf2 cz2 = (vf2){cz, cz};

        float m = -1.0f;                   // running max (v_max3 per pair)
#pragma unroll
        for (int p = 0; p < FPS_PAIRS; p++) {
            const vf2 dx = px[p] - cx2;
            const vf2 dy = py[p] - cy2;
            const vf2 dz = pz[p] - cz2;
            vf2 s = dx * dx + dy * dy;     // contract off => mul,mul,add
            s = s + dz * dz;               // ((x^2+y^2)+z^2) order
            vf2 d;
            d.x = fminf(dd[p].x, s.x);
            d.y = fminf(dd[p].y, s.y);
            dd[p] = d;
            m = fmaxf(m, fmaxf(d.x, d.y)); // folds to v_max3_f32
        }
        const float bv = m;

        // reverse scan: lowest j with dd[j] == bv (max is a selection =>
        // exact bitwise compare); n = tid*16 + j so min j == min n in-lane
        int bj = 0;
#pragma unroll
        for (int j = 15; j >= 0; j--) {
            const float v = (j & 1) ? dd[j >> 1].y : dd[j >> 1].x;
            if (v == bv) bj = j;
        }
        const int bn = (tid << 4) | bj;    // global point index

        // wave argmax: f32 chain + ballot + first-lane readback
        const float wm = wave_fmax63(bv);
        const float wmax = __int_as_float(
            __builtin_amdgcn_readlane(__float_as_int(wm), 63));
        const unsigned long long mask = __ballot(bv == wmax);
        const int first = __ffsll(mask) - 1;
        const unsigned nw = (unsigned)__builtin_amdgcn_readlane(bn, first);

        const unsigned long long wkey =
            ((unsigned long long)__float_as_uint(wmax) << 32) |
            (unsigned long long)(4095u - nw);

        const int par = i & 1;
        if (lane == 0) ckey[par][wid] = wkey;
        __syncthreads();

        // all threads redundantly resolve the 4-way final (no 2nd barrier:
        // parity double-buffer makes the next write race-free)
        const ulonglong2* kb = (const ulonglong2*)(&ckey[par][0]);
        const ulonglong2 k01 = kb[0], k23 = kb[1];
        const unsigned long long kk =
            kmax2(kmax2(k01.x, k01.y), kmax2(k23.x, k23.y));

        ci = (int)(4095u - (unsigned)kk);
        const float4 c = sp[ci];
        cx = c.x; cy = c.y; cz = c.z;
    }
    __syncthreads();

    // epilogue: coalesced writes of cents + vertices_pool
    for (int i = tid; i < NPOINT; i += FPS_T) {
        const int cc = scent[i];
        const float4 v = sp[cc];
        cents[b * NPOINT + i] = cc;
        out_vp[(b * 3 + 0) * NPOINT + i] = v.x;
        out_vp[(b * 3 + 1) * NPOINT + i] = v.y;
        out_vp[(b * 3 + 2) * NPOINT + i] = v.z;
    }
}

// ---------------------------------------------------------------------------
// Kernel B: gather+maxpool selected rows AND transpose to (B, C, NPOINT).
// 16 waves per block; wave w pools point j0+w (64 lanes x float2 = 128 ch),
// stages the 16x128 tile in LDS, then writes channel-major 64B segments.
// ---------------------------------------------------------------------------
#define GT_J 16
__global__ __launch_bounds__(1024) void pool_gather_t(
        const float* __restrict__ fmT,     // (B*N, C)
        const int* __restrict__ idx,       // (B*N*K), values in [0, B*N)
        const int* __restrict__ cents,     // (B*NPOINT)
        float* __restrict__ out_fp)        // (B, C, NPOINT)
{
    __shared__ float tile[C_SZ][GT_J + 1];
    const int tid  = threadIdx.x;
    const int lane = tid & 63;
    const int w    = tid >> 6;
    const int j0   = blockIdx.x * GT_J;    // global pooled-point base
    const int gp   = j0 + w;
    const int b    = gp >> 10;             // NPOINT = 1024
    const int ci   = cents[gp];
    const int* ip  = idx + ((size_t)(b * N_SZ + ci)) * K_SZ;
    const float2* src = (const float2*)fmT;

    float2 acc = make_float2(-INFINITY, -INFINITY);
#pragma unroll
    for (int k = 0; k < K_SZ; k++) {
        const int p = ip[k];
        const float2 v = src[(size_t)p * (C_SZ / 2) + lane];
        acc.x = fmaxf(acc.x, v.x);
        acc.y = fmaxf(acc.y, v.y);
    }
    tile[2 * lane][w]     = acc.x;
    tile[2 * lane + 1][w] = acc.y;
    __syncthreads();

    float* q = out_fp + (size_t)b * C_SZ * NPOINT + (j0 & (NPOINT - 1));
#pragma unroll
    for (int it = 0; it < 2; it++) {
        const int e  = tid + it * 1024;
        const int c  = e >> 4;
        const int jj = e & (GT_J - 1);
        q[(size_t)c * NPOINT + jj] = tile[c][jj];
    }
}

// ---------------------------------------------------------------------------
extern "C" void kernel_launch(void* const* d_in, const int* in_sizes, int n_in,
                              void* d_out, int out_size, void* d_ws, size_t ws_size,
                              hipStream_t stream) {
    const float* verts = (const float*)d_in[0];   // (B,3,N) f32
    const float* fm    = (const float*)d_in[1];   // (B,C,N) f32
    const int*   idx   = (const int*)d_in[2];     // (B*N*K) i32

    float* out    = (float*)d_out;
    float* out_vp = out;                               // B*3*NPOINT = 24576
    float* out_fp = out + (size_t)B_SZ * 3 * NPOINT;   // B*C*NPOINT

    char* ws = (char*)d_ws;
    float* fmT   = (float*)ws;                                     // 16 MB
    int*   cents = (int*)(ws + (size_t)B_SZ * N_SZ * C_SZ * 4);    // 32 KB

    fps_fused<<<B_SZ + TR_BLOCKS, FPS_T, DYN_BYTES, stream>>>(verts, fm, fmT, out_vp, cents);
    pool_gather_t<<<(B_SZ * NPOINT) / GT_J, 1024, 0, stream>>>(fmT, idx, cents, out_fp);
}

// Round 13
// 614.935 us; speedup vs baseline: 1.0831x; 1.0128x over previous
//
#include <hip/hip_runtime.h>
#include <hip/hip_bf16.h>
#include <math.h>

// Problem constants
#define B_SZ 8
#define N_SZ 4096
#define C_SZ 128
#define K_SZ 16
#define NPOINT 1024            // N / POOL_RATE

// FPS config: 256 threads (4 waves, 1 per SIMD), 16 CONTIGUOUS points/thread
// (R8 optimum — 512thr/2-waves-per-SIMD tested twice, loses on busy growth;
//  fused-transpose companions tested thrice (R4/R10-R12), net loss)
#define FPS_T 256
#define FPS_PAIRS 8            // 8 float2-pairs = 16 points per thread

typedef float vf2 __attribute__((ext_vector_type(2)));

// ---------------------------------------------------------------------------
// Wave64 f32 max chain via DPP (full-rate).
// bound_ctrl=1 feeds 0.0 into invalid lanes — distances are >= 0 so 0 is a
// safe identity. After row_shr 1/2/4/8 + row_bcast 15/31, lane 63 = wave max.
// ---------------------------------------------------------------------------
template <int CTRL>
__device__ __forceinline__ float dpp_fmax(float x) {
    int t = __builtin_amdgcn_update_dpp(0, __float_as_int(x), CTRL, 0xF, 0xF, true);
    return fmaxf(x, __int_as_float(t));
}
__device__ __forceinline__ float wave_fmax63(float x) {
    x = dpp_fmax<0x111>(x);  // row_shr:1
    x = dpp_fmax<0x112>(x);  // row_shr:2
    x = dpp_fmax<0x114>(x);  // row_shr:4
    x = dpp_fmax<0x118>(x);  // row_shr:8
    x = dpp_fmax<0x142>(x);  // row_bcast:15
    x = dpp_fmax<0x143>(x);  // row_bcast:31
    return x;                 // valid in lane 63
}
__device__ __forceinline__ unsigned long long kmax2(unsigned long long a,
                                                   unsigned long long b) {
    return a > b ? a : b;
}

// ---------------------------------------------------------------------------
// Kernel 1: FPS, one block (256 threads, 4 waves — one per SIMD) per batch.
// Bit-exact numpy semantics: d=((x-cx)^2+(y-cy)^2)+(z-cz)^2 per-op rounding
// (contract/reassoc off), min then FIRST-index argmax.
// Thread tid owns contiguous points [tid*16, tid*16+16); wave argmax =
// f32 DPP chain -> readlane(63) -> ballot -> ffs -> readlane(bn, first);
// cross-wave via packed u64 key (dist<<32)|(4095-n); one barrier/iter.
// (R8 kernel, unchanged — 529 us standalone.)
// ---------------------------------------------------------------------------
__global__ __launch_bounds__(FPS_T) void fps_kernel(
        const float* __restrict__ verts,   // (B, 3, N)
        float* __restrict__ out_vp,        // (B, 3, NPOINT)
        int* __restrict__ cents)           // (B, NPOINT)
{
#pragma clang fp contract(off)
#pragma clang fp reassociate(off)
    __shared__ float4 sp[N_SZ];                       // 64 KB xyz (w unused)
    __shared__ int    scent[NPOINT];                  //  4 KB
    __shared__ alignas(16) unsigned long long ckey[2][4];

    const int b    = blockIdx.x;
    const int tid  = threadIdx.x;
    const int lane = tid & 63;
    const int wid  = tid >> 6;
    const float* vb = verts + (size_t)b * 3 * N_SZ;

    // stage xyz into LDS (coalesced global loads, conflict-free LDS writes)
    for (int n = tid; n < N_SZ; n += FPS_T) {
        sp[n] = make_float4(vb[n], vb[N_SZ + n], vb[2 * N_SZ + n], 0.0f);
    }

    // contiguous per-thread register copy via coalesced float4 loads
    const float4* vx4 = (const float4*)vb;
    const float4* vy4 = (const float4*)(vb + N_SZ);
    const float4* vz4 = (const float4*)(vb + 2 * N_SZ);
    vf2 px[FPS_PAIRS], py[FPS_PAIRS], pz[FPS_PAIRS], dd[FPS_PAIRS];
#pragma unroll
    for (int k = 0; k < 4; k++) {
        const float4 x = vx4[tid * 4 + k];
        const float4 y = vy4[tid * 4 + k];
        const float4 z = vz4[tid * 4 + k];
        px[2 * k] = (vf2){x.x, x.y}; px[2 * k + 1] = (vf2){x.z, x.w};
        py[2 * k] = (vf2){y.x, y.y}; py[2 * k + 1] = (vf2){y.z, y.w};
        pz[2 * k] = (vf2){z.x, z.y}; pz[2 * k + 1] = (vf2){z.z, z.w};
        dd[2 * k]     = (vf2){1e10f, 1e10f};
        dd[2 * k + 1] = (vf2){1e10f, 1e10f};
    }
    __syncthreads();

    int ci = 0;
    const float4 c0 = sp[0];
    float cx = c0.x, cy = c0.y, cz = c0.z;

    for (int i = 0; i < NPOINT; i++) {
        if (tid == 0) scent[i] = ci;

        const vf2 cx2 = (vf2){cx, cx};
        const vf2 cy2 = (vf2){cy, cy};
        const vf2 cz2 = (vf2){cz, cz};

        float m = -1.0f;                   // running max (v_max3 per pair)
#pragma unroll
        for (int p = 0; p < FPS_PAIRS; p++) {
            const vf2 dx = px[p] - cx2;
            const vf2 dy = py[p] - cy2;
            const vf2 dz = pz[p] - cz2;
            vf2 s = dx * dx + dy * dy;     // contract off => mul,mul,add
            s = s + dz * dz;               // ((x^2+y^2)+z^2) order
            vf2 d;
            d.x = fminf(dd[p].x, s.x);
            d.y = fminf(dd[p].y, s.y);
            dd[p] = d;
            m = fmaxf(m, fmaxf(d.x, d.y)); // folds to v_max3_f32
        }
        const float bv = m;

        // reverse scan: lowest j with dd[j] == bv (max is a selection =>
        // exact bitwise compare); n = tid*16 + j so min j == min n in-lane
        int bj = 0;
#pragma unroll
        for (int j = 15; j >= 0; j--) {
            const float v = (j & 1) ? dd[j >> 1].y : dd[j >> 1].x;
            if (v == bv) bj = j;
        }
        const int bn = (tid << 4) | bj;    // global point index

        // wave argmax: f32 chain + ballot + first-lane readback
        const float wm = wave_fmax63(bv);
        const float wmax = __int_as_float(
            __builtin_amdgcn_readlane(__float_as_int(wm), 63));
        const unsigned long long mask = __ballot(bv == wmax);
        const int first = __ffsll(mask) - 1;
        const unsigned nw = (unsigned)__builtin_amdgcn_readlane(bn, first);

        const unsigned long long wkey =
            ((unsigned long long)__float_as_uint(wmax) << 32) |
            (unsigned long long)(4095u - nw);

        const int par = i & 1;
        if (lane == 0) ckey[par][wid] = wkey;
        __syncthreads();

        // all threads redundantly resolve the 4-way final (no 2nd barrier:
        // parity double-buffer makes the next write race-free)
        const ulonglong2* kb = (const ulonglong2*)(&ckey[par][0]);
        const ulonglong2 k01 = kb[0], k23 = kb[1];
        const unsigned long long kk =
            kmax2(kmax2(k01.x, k01.y), kmax2(k23.x, k23.y));

        ci = (int)(4095u - (unsigned)kk);
        const float4 c = sp[ci];
        cx = c.x; cy = c.y; cz = c.z;
    }
    __syncthreads();

    // epilogue: coalesced writes of cents + vertices_pool
    for (int i = tid; i < NPOINT; i += FPS_T) {
        const int cc = scent[i];
        const float4 v = sp[cc];
        cents[b * NPOINT + i] = cc;
        out_vp[(b * 3 + 0) * NPOINT + i] = v.x;
        out_vp[(b * 3 + 1) * NPOINT + i] = v.y;
        out_vp[(b * 3 + 2) * NPOINT + i] = v.z;
    }
}

// ---------------------------------------------------------------------------
// Kernel 2: per-channel direct pooling — NO transpose, NO fmT scratch.
// Block c stages fm[:, c, :] (8*4096 floats = 128 KB) into LDS; the flat
// neighbor index p in [0, B*N) directly addresses sf[p] (layout b*4096+n ==
// p). Gather = 16 scalar LDS reads; output write out[b][c][j] is coalesced
// in j. idx/cents (~576 KB) are re-read by all 128 blocks -> L2/L3 hits.
// ---------------------------------------------------------------------------
#define PD_T 1024
__global__ __launch_bounds__(PD_T) void pool_direct(
        const float* __restrict__ fm,      // (B, C, N)
        const int* __restrict__ idx,       // (B*N*K), values in [0, B*N)
        const int* __restrict__ cents,     // (B*NPOINT)
        float* __restrict__ out_fp)        // (B, C, NPOINT)
{
    __shared__ float sf[B_SZ * N_SZ];      // 128 KB
    const int c   = blockIdx.x;            // channel
    const int tid = threadIdx.x;

    // stage fm[b][c][:] for all b (coalesced float4)
    const float4* src4 = (const float4*)fm;
    float4* sf4 = (float4*)sf;
#pragma unroll
    for (int it = 0; it < (B_SZ * N_SZ / 4) / PD_T; it++) {   // 8 iters
        const int ch = it * PD_T + tid;        // float4 chunk id
        const int b  = ch >> 10;               // 1024 chunks per batch
        const int n4 = ch & 1023;
        sf4[ch] = src4[(size_t)(b * C_SZ + c) * (N_SZ / 4) + n4];
    }
    __syncthreads();

    // gather + maxpool + direct channel-major write
#pragma unroll
    for (int it = 0; it < (B_SZ * NPOINT) / PD_T; it++) {     // 8 iters
        const int gp = it * PD_T + tid;        // global pooled-point id
        const int b  = gp >> 10;
        const int ci = cents[gp];
        const int4* ip = (const int4*)(idx + ((size_t)(b * N_SZ + ci)) * K_SZ);
        float acc = -INFINITY;
#pragma unroll
        for (int q = 0; q < 4; q++) {
            const int4 p4 = ip[q];
            acc = fmaxf(acc, sf[p4.x]);
            acc = fmaxf(acc, sf[p4.y]);
            acc = fmaxf(acc, sf[p4.z]);
            acc = fmaxf(acc, sf[p4.w]);
        }
        out_fp[(size_t)(b * C_SZ + c) * NPOINT + (gp & (NPOINT - 1))] = acc;
    }
}

// ---------------------------------------------------------------------------
extern "C" void kernel_launch(void* const* d_in, const int* in_sizes, int n_in,
                              void* d_out, int out_size, void* d_ws, size_t ws_size,
                              hipStream_t stream) {
    const float* verts = (const float*)d_in[0];   // (B,3,N) f32
    const float* fm    = (const float*)d_in[1];   // (B,C,N) f32
    const int*   idx   = (const int*)d_in[2];     // (B*N*K) i32

    float* out    = (float*)d_out;
    float* out_vp = out;                               // B*3*NPOINT = 24576
    float* out_fp = out + (size_t)B_SZ * 3 * NPOINT;   // B*C*NPOINT

    int* cents = (int*)d_ws;                           // 32 KB scratch

    fps_kernel<<<B_SZ, FPS_T, 0, stream>>>(verts, out_vp, cents);
    pool_direct<<<C_SZ, PD_T, 0, stream>>>(fm, idx, cents, out_fp);
}